// Round 1
// baseline (7829.238 us; speedup 1.0000x reference)
//
#include <hip/hip_runtime.h>
#include <hip/hip_bf16.h>
#include <cstdint>
#include <cstddef>

#define NITEMS 200000
#define NUSERS 100000
#define NINTER 2000000

// ---- bf16 helpers (bit-level, RNE) ----
__device__ __forceinline__ unsigned short f2bf(float f) {
    union { float f; unsigned u; } v; v.f = f;
    unsigned r = v.u + 0x7fffu + ((v.u >> 16) & 1u);
    return (unsigned short)(r >> 16);
}
__device__ __forceinline__ float bf2f(unsigned short h) {
    union { unsigned u; float f; } v; v.u = ((unsigned)h) << 16;
    return v.f;
}

// ============================================================================
// Kernel 1: item encoder.  x=[feat(2)|gcn(64)] -> relu(x@Wi1+bi1)@Wi2+bi2
//           -> L2 normalize -> bf16 item_emb [NITEMS,128]
// One thread = one item row. Weight accesses are wave-uniform -> s_load.
// ============================================================================
__global__ __launch_bounds__(256, 1)
void item_mlp_kernel(const float* __restrict__ item_feat,
                     const float* __restrict__ gcn_item,
                     const float* __restrict__ Wi1, const float* __restrict__ bi1,
                     const float* __restrict__ Wi2, const float* __restrict__ bi2,
                     unsigned short* __restrict__ item_emb)
{
    int i = blockIdx.x * 256 + threadIdx.x;
    if (i >= NITEMS) return;

    float x[66];
    {
        const float2 f = *reinterpret_cast<const float2*>(item_feat + (size_t)i * 2);
        x[0] = f.x; x[1] = f.y;
        const float4* g = reinterpret_cast<const float4*>(gcn_item + (size_t)i * 64);
        #pragma unroll
        for (int k = 0; k < 16; ++k) {
            float4 v = g[k];
            x[2 + 4*k + 0] = v.x; x[2 + 4*k + 1] = v.y;
            x[2 + 4*k + 2] = v.z; x[2 + 4*k + 3] = v.w;
        }
    }

    float acc[128];
    #pragma unroll
    for (int o = 0; o < 128; ++o) acc[o] = bi2[o];

    for (int j0 = 0; j0 < 256; j0 += 8) {
        float h[8];
        #pragma unroll
        for (int q = 0; q < 8; ++q) h[q] = bi1[j0 + q];
        #pragma unroll
        for (int k = 0; k < 66; ++k) {
            float xv = x[k];
            #pragma unroll
            for (int q = 0; q < 8; ++q)
                h[q] = fmaf(xv, Wi1[k * 256 + j0 + q], h[q]);
        }
        #pragma unroll
        for (int q = 0; q < 8; ++q) h[q] = fmaxf(h[q], 0.0f);
        #pragma unroll
        for (int q = 0; q < 8; ++q) {
            float hq = h[q];
            const float* w2 = Wi2 + (size_t)(j0 + q) * 128;
            #pragma unroll
            for (int o = 0; o < 128; ++o) acc[o] = fmaf(hq, w2[o], acc[o]);
        }
    }

    float ss = 0.0f;
    #pragma unroll
    for (int o = 0; o < 128; ++o) ss = fmaf(acc[o], acc[o], ss);
    float sc = 1.0f / fmaxf(sqrtf(ss), 1e-12f);

    unsigned short* dst = item_emb + (size_t)i * 128;
    #pragma unroll
    for (int o0 = 0; o0 < 128; o0 += 8) {
        uint4 p;
        p.x = (unsigned)f2bf(acc[o0+0]*sc) | ((unsigned)f2bf(acc[o0+1]*sc) << 16);
        p.y = (unsigned)f2bf(acc[o0+2]*sc) | ((unsigned)f2bf(acc[o0+3]*sc) << 16);
        p.z = (unsigned)f2bf(acc[o0+4]*sc) | ((unsigned)f2bf(acc[o0+5]*sc) << 16);
        p.w = (unsigned)f2bf(acc[o0+6]*sc) | ((unsigned)f2bf(acc[o0+7]*sc) << 16);
        *reinterpret_cast<uint4*>(dst + o0) = p;
    }
}

// ============================================================================
// Kernel 2: per-user segment start offsets via binary search (seg_ids sorted).
// start[u] = lower_bound(seg_ids, u); start[NUSERS] = NINTER naturally.
// ============================================================================
__global__ void seg_bounds_kernel(const int* __restrict__ seg,
                                  int* __restrict__ start)
{
    int u = blockIdx.x * 256 + threadIdx.x;
    if (u > NUSERS) return;
    int lo = 0, hi = NINTER;
    while (lo < hi) {
        int m = (lo + hi) >> 1;
        if (seg[m] < u) lo = m + 1; else hi = m;
    }
    start[u] = lo;
}

// ============================================================================
// Kernel 3: segment mean. One wave (64 lanes) per user; each lane owns 2 of
// the 128 columns. Row gather is one coalesced 256B load per interaction.
// ============================================================================
__global__ __launch_bounds__(256)
void seg_mean_kernel(const int* __restrict__ item_idx,
                     const int* __restrict__ start,
                     const unsigned short* __restrict__ item_emb,
                     unsigned short* __restrict__ hist)
{
    int gid  = blockIdx.x * 256 + threadIdx.x;
    int wave = gid >> 6;
    int lane = gid & 63;
    if (wave >= NUSERS) return;

    int s = start[wave], e = start[wave + 1];
    float a0 = 0.0f, a1 = 0.0f;
    for (int r = s; r < e; ++r) {
        int idx = item_idx[r];  // wave-uniform -> scalar load
        unsigned v = *reinterpret_cast<const unsigned*>(
            item_emb + (size_t)idx * 128 + lane * 2);
        a0 += bf2f((unsigned short)(v & 0xffffu));
        a1 += bf2f((unsigned short)(v >> 16));
    }
    float inv = 1.0f / fmaxf((float)(e - s), 1.0f);
    unsigned outv = (unsigned)f2bf(a0 * inv) | ((unsigned)f2bf(a1 * inv) << 16);
    *reinterpret_cast<unsigned*>(hist + (size_t)wave * 128 + lane * 2) = outv;
}

// ============================================================================
// Kernel 4: user encoder. fused=[gcn_user(64)|hist(128)] -> MLP -> L2 norm.
// One thread = one user row; f32 output.
// ============================================================================
__global__ __launch_bounds__(256, 1)
void user_mlp_kernel(const float* __restrict__ gcn_user,
                     const unsigned short* __restrict__ hist,
                     const float* __restrict__ Wu1, const float* __restrict__ bu1,
                     const float* __restrict__ Wu2, const float* __restrict__ bu2,
                     const int* __restrict__ users,
                     float* __restrict__ out)
{
    int r = blockIdx.x * 256 + threadIdx.x;
    if (r >= NUSERS) return;
    int u = users[r];

    float x[192];
    {
        const float4* g = reinterpret_cast<const float4*>(gcn_user + (size_t)u * 64);
        #pragma unroll
        for (int k = 0; k < 16; ++k) {
            float4 v = g[k];
            x[4*k+0] = v.x; x[4*k+1] = v.y; x[4*k+2] = v.z; x[4*k+3] = v.w;
        }
        const uint4* hp = reinterpret_cast<const uint4*>(hist + (size_t)u * 128);
        #pragma unroll
        for (int k = 0; k < 16; ++k) {
            uint4 v = hp[k];
            int b = 64 + 8*k;
            x[b+0] = bf2f((unsigned short)(v.x & 0xffffu)); x[b+1] = bf2f((unsigned short)(v.x >> 16));
            x[b+2] = bf2f((unsigned short)(v.y & 0xffffu)); x[b+3] = bf2f((unsigned short)(v.y >> 16));
            x[b+4] = bf2f((unsigned short)(v.z & 0xffffu)); x[b+5] = bf2f((unsigned short)(v.z >> 16));
            x[b+6] = bf2f((unsigned short)(v.w & 0xffffu)); x[b+7] = bf2f((unsigned short)(v.w >> 16));
        }
    }

    float acc[128];
    #pragma unroll
    for (int o = 0; o < 128; ++o) acc[o] = bu2[o];

    for (int j0 = 0; j0 < 256; j0 += 8) {
        float h[8];
        #pragma unroll
        for (int q = 0; q < 8; ++q) h[q] = bu1[j0 + q];
        #pragma unroll
        for (int k = 0; k < 192; ++k) {
            float xv = x[k];
            #pragma unroll
            for (int q = 0; q < 8; ++q)
                h[q] = fmaf(xv, Wu1[k * 256 + j0 + q], h[q]);
        }
        #pragma unroll
        for (int q = 0; q < 8; ++q) h[q] = fmaxf(h[q], 0.0f);
        #pragma unroll
        for (int q = 0; q < 8; ++q) {
            float hq = h[q];
            const float* w2 = Wu2 + (size_t)(j0 + q) * 128;
            #pragma unroll
            for (int o = 0; o < 128; ++o) acc[o] = fmaf(hq, w2[o], acc[o]);
        }
    }

    float ss = 0.0f;
    #pragma unroll
    for (int o = 0; o < 128; ++o) ss = fmaf(acc[o], acc[o], ss);
    float sc = 1.0f / fmaxf(sqrtf(ss), 1e-12f);

    float* dst = out + (size_t)r * 128;
    #pragma unroll
    for (int o0 = 0; o0 < 128; o0 += 4) {
        float4 v = make_float4(acc[o0]*sc, acc[o0+1]*sc, acc[o0+2]*sc, acc[o0+3]*sc);
        *reinterpret_cast<float4*>(dst + o0) = v;
    }
}

// ============================================================================
extern "C" void kernel_launch(void* const* d_in, const int* in_sizes, int n_in,
                              void* d_out, int out_size, void* d_ws, size_t ws_size,
                              hipStream_t stream)
{
    const float* item_feat = (const float*)d_in[0];
    const float* gcn_item  = (const float*)d_in[1];
    const float* gcn_user  = (const float*)d_in[2];
    const float* Wi1 = (const float*)d_in[3];
    const float* bi1 = (const float*)d_in[4];
    const float* Wi2 = (const float*)d_in[5];
    const float* bi2 = (const float*)d_in[6];
    const float* Wu1 = (const float*)d_in[7];
    const float* bu1 = (const float*)d_in[8];
    const float* Wu2 = (const float*)d_in[9];
    const float* bu2 = (const float*)d_in[10];
    const int* item_idx = (const int*)d_in[11];
    const int* seg_ids  = (const int*)d_in[12];
    const int* users    = (const int*)d_in[13];
    float* out = (float*)d_out;

    // workspace layout (all 16B-aligned):
    //   [0, 51.2MB)      item_emb  bf16 [NITEMS,128]
    //   [51.2, 76.8MB)   hist      bf16 [NUSERS,128]
    //   [76.8MB, +400KB) start     int  [NUSERS+1]
    char* ws = (char*)d_ws;
    unsigned short* item_emb = (unsigned short*)ws;
    unsigned short* hist     = (unsigned short*)(ws + (size_t)NITEMS * 128 * 2);
    int* start = (int*)(ws + (size_t)NITEMS * 128 * 2 + (size_t)NUSERS * 128 * 2);

    hipLaunchKernelGGL(item_mlp_kernel, dim3((NITEMS + 255) / 256), dim3(256), 0, stream,
                       item_feat, gcn_item, Wi1, bi1, Wi2, bi2, item_emb);

    hipLaunchKernelGGL(seg_bounds_kernel, dim3((NUSERS + 1 + 255) / 256), dim3(256), 0, stream,
                       seg_ids, start);

    hipLaunchKernelGGL(seg_mean_kernel, dim3(NUSERS / 4), dim3(256), 0, stream,
                       item_idx, start, item_emb, hist);

    hipLaunchKernelGGL(user_mlp_kernel, dim3((NUSERS + 255) / 256), dim3(256), 0, stream,
                       gcn_user, hist, Wu1, bu1, Wu2, bu2, users, out);
}

// Round 3
// 474.976 us; speedup vs baseline: 16.4834x; 16.4834x over previous
//
#include <hip/hip_runtime.h>
#include <hip/hip_bf16.h>
#include <cstdint>
#include <cstddef>

#define NITEMS 200000
#define NUSERS 100000
#define NINTER 2000000

typedef __attribute__((ext_vector_type(8))) short bf16x8;
typedef __attribute__((ext_vector_type(4))) float f32x4;

// ---- bf16 helpers (bit-level, RNE) ----
__device__ __forceinline__ unsigned short f2bf(float f) {
    union { float f; unsigned u; } v; v.f = f;
    unsigned r = v.u + 0x7fffu + ((v.u >> 16) & 1u);
    return (unsigned short)(r >> 16);
}
__device__ __forceinline__ float bf2f(unsigned short h) {
    union { unsigned u; float f; } v; v.u = ((unsigned)h) << 16;
    return v.f;
}
__device__ __forceinline__ unsigned pack2(float a, float b) {
    return (unsigned)f2bf(a) | ((unsigned)f2bf(b) << 16);
}

// ============================================================================
// Kernel 0: transpose + convert weights to bf16 [N][K] so each lane's MFMA
// B-fragment (B[k = 8*(l>>4)+j][n = l&15]) is one contiguous 16B load.
//   W1t  [256][96]  <- Wi1 [66][256], K padded 66->96 with zeros
//   W2t  [128][256] <- Wi2 [256][128]
//   W1ut [256][192] <- Wu1 [192][256]
//   W2ut [128][256] <- Wu2 [256][128]
// ============================================================================
__global__ void preconv_kernel(const float* __restrict__ Wi1, const float* __restrict__ Wi2,
                               const float* __restrict__ Wu1, const float* __restrict__ Wu2,
                               unsigned short* __restrict__ W1t, unsigned short* __restrict__ W2t,
                               unsigned short* __restrict__ W1ut, unsigned short* __restrict__ W2ut)
{
    int t = blockIdx.x * 256 + threadIdx.x;
    if (t < 256 * 96) {
        int n = t / 96, k = t % 96;
        W1t[t] = (k < 66) ? f2bf(Wi1[k * 256 + n]) : (unsigned short)0;
        return;
    }
    t -= 256 * 96;
    if (t < 128 * 256) {
        int n = t / 256, k = t % 256;
        W2t[t] = f2bf(Wi2[k * 128 + n]);
        return;
    }
    t -= 128 * 256;
    if (t < 256 * 192) {
        int n = t / 192, k = t % 192;
        W1ut[t] = f2bf(Wu1[k * 256 + n]);
        return;
    }
    t -= 256 * 192;
    if (t < 128 * 256) {
        int n = t / 256, k = t % 256;
        W2ut[t] = f2bf(Wu2[k * 128 + n]);
    }
}

#define HS 280     // H LDS stride in bf16 (256 + 24 pad: 2-way-max frag reads, 16B aligned)

// ============================================================================
// Kernel 1: item encoder via MFMA. 64 rows/block, 4 waves.
// Layer1: X[64,96]@W1[96,256] (wave w owns cols 64w..64w+64); relu -> H LDS bf16.
// Layer2: H[64,256]@W2[256,128] (wave w owns cols 32w..32w+32); L2norm -> bf16.
// ============================================================================
#define XS_I 120   // X stride bf16 (96 + 24 pad)

__global__ __launch_bounds__(256, 2)
void item_mfma_kernel(const float* __restrict__ item_feat,
                      const float* __restrict__ gcn_item,
                      const unsigned short* __restrict__ W1t,
                      const unsigned short* __restrict__ W2t,
                      const float* __restrict__ bi1, const float* __restrict__ bi2,
                      unsigned short* __restrict__ item_emb)
{
    __shared__ unsigned short Xs[64 * XS_I];
    __shared__ unsigned short Hs[64 * HS];
    __shared__ float ssq[64][4];

    const int t  = threadIdx.x;
    const int w  = t >> 6;
    const int l  = t & 63;
    const int lo = l & 15;
    const int hi = l >> 4;
    const size_t i0 = (size_t)blockIdx.x * 64;

    // ---- stage X (bf16): cols 0-1 feat, 2-65 gcn, 66-95 zero pad ----
    {
        const int row = t >> 2, q = t & 3;
        const float4* g = (const float4*)(gcn_item + (i0 + row) * 64 + q * 16);
        unsigned* dst = (unsigned*)((char*)Xs + row * (XS_I * 2) + 4 + q * 32);
        #pragma unroll
        for (int k = 0; k < 4; ++k) {
            float4 v = g[k];
            dst[2 * k]     = pack2(v.x, v.y);
            dst[2 * k + 1] = pack2(v.z, v.w);
        }
        if (t < 64) {
            float2 f = *(const float2*)(item_feat + (i0 + t) * 2);
            *(unsigned*)((char*)Xs + t * (XS_I * 2)) = pack2(f.x, f.y);
            unsigned* z = (unsigned*)((char*)Xs + t * (XS_I * 2) + 132);
            #pragma unroll
            for (int k = 0; k < 15; ++k) z[k] = 0u;
        }
    }

    // ---- W1 fragments in registers: 4 coltiles x 3 ktiles (48 VGPR) ----
    bf16x8 w1f[4][3];
    #pragma unroll
    for (int ct = 0; ct < 4; ++ct)
        #pragma unroll
        for (int kt = 0; kt < 3; ++kt) {
            int n = 64 * w + ct * 16 + lo;
            w1f[ct][kt] = *(const bf16x8*)(W1t + n * 96 + kt * 32 + hi * 8);
        }
    // ---- W2 fragments: 2 coltiles x 8 ktiles (64 VGPR), issued early ----
    bf16x8 w2f[2][8];
    #pragma unroll
    for (int ct = 0; ct < 2; ++ct)
        #pragma unroll
        for (int kt = 0; kt < 8; ++kt) {
            int n = 32 * w + ct * 16 + lo;
            w2f[ct][kt] = *(const bf16x8*)(W2t + n * 256 + kt * 32 + hi * 8);
        }

    __syncthreads();

    // ---- layer 1 MFMA ----
    f32x4 acc1[4][4];
    #pragma unroll
    for (int rt = 0; rt < 4; ++rt)
        #pragma unroll
        for (int ct = 0; ct < 4; ++ct)
            acc1[rt][ct] = (f32x4)(0.0f);

    #pragma unroll
    for (int rt = 0; rt < 4; ++rt) {
        #pragma unroll
        for (int kt = 0; kt < 3; ++kt) {
            bf16x8 a = *(const bf16x8*)((char*)Xs + (rt * 16 + lo) * (XS_I * 2) + kt * 64 + hi * 16);
            #pragma unroll
            for (int ct = 0; ct < 4; ++ct)
                acc1[rt][ct] = __builtin_amdgcn_mfma_f32_16x16x32_bf16(a, w1f[ct][kt], acc1[rt][ct], 0, 0, 0);
        }
    }

    // ---- bias + relu + write H (bf16) ----
    {
        float b1v[4];
        #pragma unroll
        for (int ct = 0; ct < 4; ++ct) b1v[ct] = bi1[64 * w + ct * 16 + lo];
        #pragma unroll
        for (int rt = 0; rt < 4; ++rt)
            #pragma unroll
            for (int ct = 0; ct < 4; ++ct)
                #pragma unroll
                for (int r = 0; r < 4; ++r) {
                    float h = fmaxf(acc1[rt][ct][r] + b1v[ct], 0.0f);
                    Hs[(rt * 16 + 4 * hi + r) * HS + 64 * w + ct * 16 + lo] = f2bf(h);
                }
    }
    __syncthreads();

    // ---- layer 2 MFMA ----
    f32x4 acc2[4][2];
    #pragma unroll
    for (int rt = 0; rt < 4; ++rt) {
        acc2[rt][0] = (f32x4)(0.0f);
        acc2[rt][1] = (f32x4)(0.0f);
    }
    #pragma unroll
    for (int rt = 0; rt < 4; ++rt) {
        #pragma unroll
        for (int kt = 0; kt < 8; ++kt) {
            bf16x8 a = *(const bf16x8*)((char*)Hs + (rt * 16 + lo) * (HS * 2) + kt * 64 + hi * 16);
            #pragma unroll
            for (int ct = 0; ct < 2; ++ct)
                acc2[rt][ct] = __builtin_amdgcn_mfma_f32_16x16x32_bf16(a, w2f[ct][kt], acc2[rt][ct], 0, 0, 0);
        }
    }

    // ---- bias, row sum-of-squares (16-lane shuffle + cross-wave LDS), norm, store ----
    float b2v[2];
    b2v[0] = bi2[32 * w + lo];
    b2v[1] = bi2[32 * w + 16 + lo];
    #pragma unroll
    for (int rt = 0; rt < 4; ++rt)
        #pragma unroll
        for (int r = 0; r < 4; ++r) {
            float v0 = acc2[rt][0][r] + b2v[0];
            float v1 = acc2[rt][1][r] + b2v[1];
            acc2[rt][0][r] = v0;
            acc2[rt][1][r] = v1;
            float p = v0 * v0 + v1 * v1;
            p += __shfl_xor(p, 1);
            p += __shfl_xor(p, 2);
            p += __shfl_xor(p, 4);
            p += __shfl_xor(p, 8);
            if (lo == 0) ssq[rt * 16 + 4 * hi + r][w] = p;
        }
    __syncthreads();

    #pragma unroll
    for (int rt = 0; rt < 4; ++rt)
        #pragma unroll
        for (int r = 0; r < 4; ++r) {
            int row = rt * 16 + 4 * hi + r;
            float4 s4 = *(const float4*)&ssq[row][0];
            float tot = s4.x + s4.y + s4.z + s4.w;
            float sc = 1.0f / fmaxf(sqrtf(tot), 1e-12f);
            unsigned short* dst = item_emb + (i0 + row) * 128 + 32 * w + lo;
            dst[0]  = f2bf(acc2[rt][0][r] * sc);
            dst[16] = f2bf(acc2[rt][1][r] * sc);
        }
}

// ============================================================================
// Kernel 2: segment offsets (binary search over sorted seg_ids)
// ============================================================================
__global__ void seg_bounds_kernel(const int* __restrict__ seg, int* __restrict__ start)
{
    int u = blockIdx.x * 256 + threadIdx.x;
    if (u > NUSERS) return;
    int lo = 0, hi = NINTER;
    while (lo < hi) {
        int m = (lo + hi) >> 1;
        if (seg[m] < u) lo = m + 1; else hi = m;
    }
    start[u] = lo;
}

// ============================================================================
// Kernel 3: segment mean (one wave per user; lane owns 2 columns)
// ============================================================================
__global__ __launch_bounds__(256)
void seg_mean_kernel(const int* __restrict__ item_idx,
                     const int* __restrict__ start,
                     const unsigned short* __restrict__ item_emb,
                     unsigned short* __restrict__ hist)
{
    int gid  = blockIdx.x * 256 + threadIdx.x;
    int wave = gid >> 6;
    int lane = gid & 63;
    if (wave >= NUSERS) return;

    int s = start[wave], e = start[wave + 1];
    float a0 = 0.0f, a1 = 0.0f;
    for (int r = s; r < e; ++r) {
        int idx = item_idx[r];
        unsigned v = *(const unsigned*)(item_emb + (size_t)idx * 128 + lane * 2);
        a0 += bf2f((unsigned short)(v & 0xffffu));
        a1 += bf2f((unsigned short)(v >> 16));
    }
    float inv = 1.0f / fmaxf((float)(e - s), 1.0f);
    unsigned outv = (unsigned)f2bf(a0 * inv) | ((unsigned)f2bf(a1 * inv) << 16);
    *(unsigned*)(hist + (size_t)wave * 128 + lane * 2) = outv;
}

// ============================================================================
// Kernel 4: user encoder via MFMA. Same structure as item; K1=192 exact.
// ============================================================================
#define XS_U 216   // X stride bf16 (192 + 24 pad)

__global__ __launch_bounds__(256, 2)
void user_mfma_kernel(const float* __restrict__ gcn_user,
                      const unsigned short* __restrict__ hist,
                      const unsigned short* __restrict__ W1ut,
                      const unsigned short* __restrict__ W2ut,
                      const float* __restrict__ bu1, const float* __restrict__ bu2,
                      const int* __restrict__ users,
                      float* __restrict__ out)
{
    __shared__ unsigned short Xs[64 * XS_U];
    __shared__ unsigned short Hs[64 * HS];
    __shared__ float ssq[64][4];

    const int t  = threadIdx.x;
    const int w  = t >> 6;
    const int l  = t & 63;
    const int lo = l & 15;
    const int hi = l >> 4;
    const int r0 = blockIdx.x * 64;

    // ---- stage X: cols 0-63 gcn_user (f32->bf16), 64-191 hist (bf16 copy) ----
    {
        const int row = t >> 2, q = t & 3;
        int rr = r0 + row;
        int u = users[rr < NUSERS ? rr : (NUSERS - 1)];
        const float4* g = (const float4*)(gcn_user + (size_t)u * 64 + q * 16);
        unsigned* dst = (unsigned*)((char*)Xs + row * (XS_U * 2) + q * 32);
        #pragma unroll
        for (int k = 0; k < 4; ++k) {
            float4 v = g[k];
            dst[2 * k]     = pack2(v.x, v.y);
            dst[2 * k + 1] = pack2(v.z, v.w);
        }
        const uint4* hp = (const uint4*)(hist + (size_t)u * 128 + q * 32);
        uint4* hd = (uint4*)((char*)Xs + row * (XS_U * 2) + 128 + q * 64);
        #pragma unroll
        for (int k = 0; k < 4; ++k) hd[k] = hp[k];
    }

    // ---- W1u fragments: 4 coltiles x 6 ktiles (96 VGPR) ----
    bf16x8 w1f[4][6];
    #pragma unroll
    for (int ct = 0; ct < 4; ++ct)
        #pragma unroll
        for (int kt = 0; kt < 6; ++kt) {
            int n = 64 * w + ct * 16 + lo;
            w1f[ct][kt] = *(const bf16x8*)(W1ut + n * 192 + kt * 32 + hi * 8);
        }

    __syncthreads();

    // ---- layer 1 ----
    f32x4 acc1[4][4];
    #pragma unroll
    for (int rt = 0; rt < 4; ++rt)
        #pragma unroll
        for (int ct = 0; ct < 4; ++ct)
            acc1[rt][ct] = (f32x4)(0.0f);

    #pragma unroll
    for (int rt = 0; rt < 4; ++rt) {
        #pragma unroll
        for (int kt = 0; kt < 6; ++kt) {
            bf16x8 a = *(const bf16x8*)((char*)Xs + (rt * 16 + lo) * (XS_U * 2) + kt * 64 + hi * 16);
            #pragma unroll
            for (int ct = 0; ct < 4; ++ct)
                acc1[rt][ct] = __builtin_amdgcn_mfma_f32_16x16x32_bf16(a, w1f[ct][kt], acc1[rt][ct], 0, 0, 0);
        }
    }

    {
        float b1v[4];
        #pragma unroll
        for (int ct = 0; ct < 4; ++ct) b1v[ct] = bu1[64 * w + ct * 16 + lo];
        #pragma unroll
        for (int rt = 0; rt < 4; ++rt)
            #pragma unroll
            for (int ct = 0; ct < 4; ++ct)
                #pragma unroll
                for (int r = 0; r < 4; ++r) {
                    float h = fmaxf(acc1[rt][ct][r] + b1v[ct], 0.0f);
                    Hs[(rt * 16 + 4 * hi + r) * HS + 64 * w + ct * 16 + lo] = f2bf(h);
                }
    }

    // ---- W2u fragments loaded after layer 1 (keeps VGPR peak < 256) ----
    bf16x8 w2f[2][8];
    #pragma unroll
    for (int ct = 0; ct < 2; ++ct)
        #pragma unroll
        for (int kt = 0; kt < 8; ++kt) {
            int n = 32 * w + ct * 16 + lo;
            w2f[ct][kt] = *(const bf16x8*)(W2ut + n * 256 + kt * 32 + hi * 8);
        }
    __syncthreads();

    // ---- layer 2 ----
    f32x4 acc2[4][2];
    #pragma unroll
    for (int rt = 0; rt < 4; ++rt) {
        acc2[rt][0] = (f32x4)(0.0f);
        acc2[rt][1] = (f32x4)(0.0f);
    }
    #pragma unroll
    for (int rt = 0; rt < 4; ++rt) {
        #pragma unroll
        for (int kt = 0; kt < 8; ++kt) {
            bf16x8 a = *(const bf16x8*)((char*)Hs + (rt * 16 + lo) * (HS * 2) + kt * 64 + hi * 16);
            #pragma unroll
            for (int ct = 0; ct < 2; ++ct)
                acc2[rt][ct] = __builtin_amdgcn_mfma_f32_16x16x32_bf16(a, w2f[ct][kt], acc2[rt][ct], 0, 0, 0);
        }
    }

    // ---- bias, L2 norm, f32 store ----
    float b2v[2];
    b2v[0] = bu2[32 * w + lo];
    b2v[1] = bu2[32 * w + 16 + lo];
    #pragma unroll
    for (int rt = 0; rt < 4; ++rt)
        #pragma unroll
        for (int r = 0; r < 4; ++r) {
            float v0 = acc2[rt][0][r] + b2v[0];
            float v1 = acc2[rt][1][r] + b2v[1];
            acc2[rt][0][r] = v0;
            acc2[rt][1][r] = v1;
            float p = v0 * v0 + v1 * v1;
            p += __shfl_xor(p, 1);
            p += __shfl_xor(p, 2);
            p += __shfl_xor(p, 4);
            p += __shfl_xor(p, 8);
            if (lo == 0) ssq[rt * 16 + 4 * hi + r][w] = p;
        }
    __syncthreads();

    #pragma unroll
    for (int rt = 0; rt < 4; ++rt)
        #pragma unroll
        for (int r = 0; r < 4; ++r) {
            int row = rt * 16 + 4 * hi + r;
            if (r0 + row >= NUSERS) continue;
            float4 s4 = *(const float4*)&ssq[row][0];
            float tot = s4.x + s4.y + s4.z + s4.w;
            float sc = 1.0f / fmaxf(sqrtf(tot), 1e-12f);
            float* dst = out + (size_t)(r0 + row) * 128 + 32 * w + lo;
            dst[0]  = acc2[rt][0][r] * sc;
            dst[16] = acc2[rt][1][r] * sc;
        }
}

// ============================================================================
extern "C" void kernel_launch(void* const* d_in, const int* in_sizes, int n_in,
                              void* d_out, int out_size, void* d_ws, size_t ws_size,
                              hipStream_t stream)
{
    const float* item_feat = (const float*)d_in[0];
    const float* gcn_item  = (const float*)d_in[1];
    const float* gcn_user  = (const float*)d_in[2];
    const float* Wi1 = (const float*)d_in[3];
    const float* bi1 = (const float*)d_in[4];
    const float* Wi2 = (const float*)d_in[5];
    const float* bi2 = (const float*)d_in[6];
    const float* Wu1 = (const float*)d_in[7];
    const float* bu1 = (const float*)d_in[8];
    const float* Wu2 = (const float*)d_in[9];
    const float* bu2 = (const float*)d_in[10];
    const int* item_idx = (const int*)d_in[11];
    const int* seg_ids  = (const int*)d_in[12];
    const int* users    = (const int*)d_in[13];
    float* out = (float*)d_out;

    // workspace layout
    char* ws = (char*)d_ws;
    unsigned short* item_emb = (unsigned short*)ws;                         // 51.2 MB
    unsigned short* hist = (unsigned short*)(ws + (size_t)NITEMS * 256);    // 25.6 MB
    size_t off = (size_t)NITEMS * 256 + (size_t)NUSERS * 256;
    int* start = (int*)(ws + off);                                          // 400 KB
    off += ((size_t)(NUSERS + 1) * 4 + 255) & ~(size_t)255;
    unsigned short* W1t  = (unsigned short*)(ws + off); off += 256 * 96 * 2;
    unsigned short* W2t  = (unsigned short*)(ws + off); off += 128 * 256 * 2;
    unsigned short* W1ut = (unsigned short*)(ws + off); off += 256 * 192 * 2;
    unsigned short* W2ut = (unsigned short*)(ws + off);

    hipLaunchKernelGGL(preconv_kernel, dim3(544), dim3(256), 0, stream,
                       Wi1, Wi2, Wu1, Wu2, W1t, W2t, W1ut, W2ut);

    hipLaunchKernelGGL(seg_bounds_kernel, dim3((NUSERS + 1 + 255) / 256), dim3(256), 0, stream,
                       seg_ids, start);

    hipLaunchKernelGGL(item_mfma_kernel, dim3(NITEMS / 64), dim3(256), 0, stream,
                       item_feat, gcn_item, W1t, W2t, bi1, bi2, item_emb);

    hipLaunchKernelGGL(seg_mean_kernel, dim3(NUSERS / 4), dim3(256), 0, stream,
                       item_idx, start, item_emb, hist);

    hipLaunchKernelGGL(user_mfma_kernel, dim3((NUSERS + 63) / 64), dim3(256), 0, stream,
                       gcn_user, hist, W1ut, W2ut, bu1, bu2, users, out);
}

// Round 5
// 362.006 us; speedup vs baseline: 21.6274x; 1.3121x over previous
//
#include <hip/hip_runtime.h>
#include <hip/hip_bf16.h>
#include <cstdint>
#include <cstddef>

#define NITEMS 200000
#define NUSERS 100000
#define NINTER 2000000

typedef __attribute__((ext_vector_type(8))) short bf16x8;
typedef __attribute__((ext_vector_type(4))) float f32x4;

// ---- bf16 helpers (bit-level, RNE) ----
__device__ __forceinline__ unsigned short f2bf(float f) {
    union { float f; unsigned u; } v; v.f = f;
    unsigned r = v.u + 0x7fffu + ((v.u >> 16) & 1u);
    return (unsigned short)(r >> 16);
}
__device__ __forceinline__ float bf2f(unsigned short h) {
    union { unsigned u; float f; } v; v.u = ((unsigned)h) << 16;
    return v.f;
}
__device__ __forceinline__ unsigned pack2(float a, float b) {
    return (unsigned)f2bf(a) | ((unsigned)f2bf(b) << 16);
}

// ============================================================================
// Kernel 0: transpose + convert weights to bf16 [N][K] so each lane's MFMA
// B-fragment (B[k = 8*(l>>4)+j][n = l&15]) is one contiguous 16B load.
// ============================================================================
__global__ void preconv_kernel(const float* __restrict__ Wi1, const float* __restrict__ Wi2,
                               const float* __restrict__ Wu1, const float* __restrict__ Wu2,
                               unsigned short* __restrict__ W1t, unsigned short* __restrict__ W2t,
                               unsigned short* __restrict__ W1ut, unsigned short* __restrict__ W2ut)
{
    int t = blockIdx.x * 256 + threadIdx.x;
    if (t < 256 * 96) {
        int n = t / 96, k = t % 96;
        W1t[t] = (k < 66) ? f2bf(Wi1[k * 256 + n]) : (unsigned short)0;
        return;
    }
    t -= 256 * 96;
    if (t < 128 * 256) {
        int n = t / 256, k = t % 256;
        W2t[t] = f2bf(Wi2[k * 128 + n]);
        return;
    }
    t -= 128 * 256;
    if (t < 256 * 192) {
        int n = t / 192, k = t % 192;
        W1ut[t] = f2bf(Wu1[k * 256 + n]);
        return;
    }
    t -= 256 * 192;
    if (t < 128 * 256) {
        int n = t / 256, k = t % 256;
        W2ut[t] = f2bf(Wu2[k * 128 + n]);
    }
}

#define HS 280     // H LDS stride in bf16 (256 + 24 pad: 2-way-max frag reads, 16B aligned)

// ============================================================================
// Kernel 1: item encoder via MFMA. 64 rows/block, 4 waves.
// ============================================================================
#define XS_I 120   // X stride bf16 (96 + 24 pad)

__global__ __launch_bounds__(256, 2)
void item_mfma_kernel(const float* __restrict__ item_feat,
                      const float* __restrict__ gcn_item,
                      const unsigned short* __restrict__ W1t,
                      const unsigned short* __restrict__ W2t,
                      const float* __restrict__ bi1, const float* __restrict__ bi2,
                      unsigned short* __restrict__ item_emb)
{
    __shared__ unsigned short Xs[64 * XS_I];
    __shared__ unsigned short Hs[64 * HS];
    __shared__ float ssq[64][4];

    const int t  = threadIdx.x;
    const int w  = t >> 6;
    const int l  = t & 63;
    const int lo = l & 15;
    const int hi = l >> 4;
    const size_t i0 = (size_t)blockIdx.x * 64;

    // ---- stage X (bf16): cols 0-1 feat, 2-65 gcn, 66-95 zero pad ----
    {
        const int row = t >> 2, q = t & 3;
        const float4* g = (const float4*)(gcn_item + (i0 + row) * 64 + q * 16);
        unsigned* dst = (unsigned*)((char*)Xs + row * (XS_I * 2) + 4 + q * 32);
        #pragma unroll
        for (int k = 0; k < 4; ++k) {
            float4 v = g[k];
            dst[2 * k]     = pack2(v.x, v.y);
            dst[2 * k + 1] = pack2(v.z, v.w);
        }
        if (t < 64) {
            float2 f = *(const float2*)(item_feat + (i0 + t) * 2);
            *(unsigned*)((char*)Xs + t * (XS_I * 2)) = pack2(f.x, f.y);
            unsigned* z = (unsigned*)((char*)Xs + t * (XS_I * 2) + 132);
            #pragma unroll
            for (int k = 0; k < 15; ++k) z[k] = 0u;
        }
    }

    // ---- W1 fragments in registers: 4 coltiles x 3 ktiles ----
    bf16x8 w1f[4][3];
    #pragma unroll
    for (int ct = 0; ct < 4; ++ct)
        #pragma unroll
        for (int kt = 0; kt < 3; ++kt) {
            int n = 64 * w + ct * 16 + lo;
            w1f[ct][kt] = *(const bf16x8*)(W1t + n * 96 + kt * 32 + hi * 8);
        }
    // ---- W2 fragments: 2 coltiles x 8 ktiles ----
    bf16x8 w2f[2][8];
    #pragma unroll
    for (int ct = 0; ct < 2; ++ct)
        #pragma unroll
        for (int kt = 0; kt < 8; ++kt) {
            int n = 32 * w + ct * 16 + lo;
            w2f[ct][kt] = *(const bf16x8*)(W2t + n * 256 + kt * 32 + hi * 8);
        }

    __syncthreads();

    // ---- layer 1 MFMA ----
    f32x4 acc1[4][4];
    #pragma unroll
    for (int rt = 0; rt < 4; ++rt)
        #pragma unroll
        for (int ct = 0; ct < 4; ++ct)
            acc1[rt][ct] = (f32x4)(0.0f);

    #pragma unroll
    for (int rt = 0; rt < 4; ++rt) {
        #pragma unroll
        for (int kt = 0; kt < 3; ++kt) {
            bf16x8 a = *(const bf16x8*)((char*)Xs + (rt * 16 + lo) * (XS_I * 2) + kt * 64 + hi * 16);
            #pragma unroll
            for (int ct = 0; ct < 4; ++ct)
                acc1[rt][ct] = __builtin_amdgcn_mfma_f32_16x16x32_bf16(a, w1f[ct][kt], acc1[rt][ct], 0, 0, 0);
        }
    }

    // ---- bias + relu + write H (bf16) ----
    {
        float b1v[4];
        #pragma unroll
        for (int ct = 0; ct < 4; ++ct) b1v[ct] = bi1[64 * w + ct * 16 + lo];
        #pragma unroll
        for (int rt = 0; rt < 4; ++rt)
            #pragma unroll
            for (int ct = 0; ct < 4; ++ct)
                #pragma unroll
                for (int r = 0; r < 4; ++r) {
                    float h = fmaxf(acc1[rt][ct][r] + b1v[ct], 0.0f);
                    Hs[(rt * 16 + 4 * hi + r) * HS + 64 * w + ct * 16 + lo] = f2bf(h);
                }
    }
    __syncthreads();

    // ---- layer 2 MFMA ----
    f32x4 acc2[4][2];
    #pragma unroll
    for (int rt = 0; rt < 4; ++rt) {
        acc2[rt][0] = (f32x4)(0.0f);
        acc2[rt][1] = (f32x4)(0.0f);
    }
    #pragma unroll
    for (int rt = 0; rt < 4; ++rt) {
        #pragma unroll
        for (int kt = 0; kt < 8; ++kt) {
            bf16x8 a = *(const bf16x8*)((char*)Hs + (rt * 16 + lo) * (HS * 2) + kt * 64 + hi * 16);
            #pragma unroll
            for (int ct = 0; ct < 2; ++ct)
                acc2[rt][ct] = __builtin_amdgcn_mfma_f32_16x16x32_bf16(a, w2f[ct][kt], acc2[rt][ct], 0, 0, 0);
        }
    }

    // ---- bias, row sum-of-squares, norm, store ----
    float b2v[2];
    b2v[0] = bi2[32 * w + lo];
    b2v[1] = bi2[32 * w + 16 + lo];
    #pragma unroll
    for (int rt = 0; rt < 4; ++rt)
        #pragma unroll
        for (int r = 0; r < 4; ++r) {
            float v0 = acc2[rt][0][r] + b2v[0];
            float v1 = acc2[rt][1][r] + b2v[1];
            acc2[rt][0][r] = v0;
            acc2[rt][1][r] = v1;
            float p = v0 * v0 + v1 * v1;
            p += __shfl_xor(p, 1);
            p += __shfl_xor(p, 2);
            p += __shfl_xor(p, 4);
            p += __shfl_xor(p, 8);
            if (lo == 0) ssq[rt * 16 + 4 * hi + r][w] = p;
        }
    __syncthreads();

    #pragma unroll
    for (int rt = 0; rt < 4; ++rt)
        #pragma unroll
        for (int r = 0; r < 4; ++r) {
            int row = rt * 16 + 4 * hi + r;
            float4 s4 = *(const float4*)&ssq[row][0];
            float tot = s4.x + s4.y + s4.z + s4.w;
            float sc = 1.0f / fmaxf(sqrtf(tot), 1e-12f);
            unsigned short* dst = item_emb + (i0 + row) * 128 + 32 * w + lo;
            dst[0]  = f2bf(acc2[rt][0][r] * sc);
            dst[16] = f2bf(acc2[rt][1][r] * sc);
        }
}

// ============================================================================
// Kernel 2: segment offsets (binary search over sorted seg_ids)
// ============================================================================
__global__ void seg_bounds_kernel(const int* __restrict__ seg, int* __restrict__ start)
{
    int u = blockIdx.x * 256 + threadIdx.x;
    if (u > NUSERS) return;
    int lo = 0, hi = NINTER;
    while (lo < hi) {
        int m = (lo + hi) >> 1;
        if (seg[m] < u) lo = m + 1; else hi = m;
    }
    start[u] = lo;
}

// ============================================================================
// Kernel 3: segment mean — software-pipelined gather.
// One wave per user; lane owns 2 of 128 columns (one dword per row).
// Unroll x4 with next-group idx prefetch: 4 row loads always in flight,
// idx latency hidden under previous group. Tail via clamped dup loads + mask.
// ============================================================================
__global__ __launch_bounds__(256)
void seg_mean_kernel(const int* __restrict__ item_idx,
                     const int* __restrict__ start,
                     const unsigned short* __restrict__ item_emb,
                     unsigned short* __restrict__ hist)
{
    int gid  = blockIdx.x * 256 + threadIdx.x;
    int wave = gid >> 6;
    int lane = gid & 63;
    if (wave >= NUSERS) return;

    int s = start[wave], e = start[wave + 1];
    int n = e - s;
    float a0 = 0.0f, a1 = 0.0f;

    if (n > 0) {
        const int elast = e - 1;
        // prefetch first idx group (clamped: duplicates hit cache)
        int i0 = item_idx[s];
        int i1 = item_idx[min(s + 1, elast)];
        int i2 = item_idx[min(s + 2, elast)];
        int i3 = item_idx[min(s + 3, elast)];
        for (int r = s; r < e; r += 4) {
            const int j0 = i0, j1 = i1, j2 = i2, j3 = i3;
            int rn = r + 4;
            if (rn < e) {  // prefetch next idx group before consuming rows
                i0 = item_idx[rn];
                i1 = item_idx[min(rn + 1, elast)];
                i2 = item_idx[min(rn + 2, elast)];
                i3 = item_idx[min(rn + 3, elast)];
            }
            unsigned v0 = *(const unsigned*)(item_emb + (size_t)j0 * 128 + lane * 2);
            unsigned v1 = *(const unsigned*)(item_emb + (size_t)j1 * 128 + lane * 2);
            unsigned v2 = *(const unsigned*)(item_emb + (size_t)j2 * 128 + lane * 2);
            unsigned v3 = *(const unsigned*)(item_emb + (size_t)j3 * 128 + lane * 2);
            const float m1 = (r + 1 < e) ? 1.0f : 0.0f;
            const float m2 = (r + 2 < e) ? 1.0f : 0.0f;
            const float m3 = (r + 3 < e) ? 1.0f : 0.0f;
            a0 += bf2f((unsigned short)(v0 & 0xffffu));
            a1 += bf2f((unsigned short)(v0 >> 16));
            a0 = fmaf(m1, bf2f((unsigned short)(v1 & 0xffffu)), a0);
            a1 = fmaf(m1, bf2f((unsigned short)(v1 >> 16)), a1);
            a0 = fmaf(m2, bf2f((unsigned short)(v2 & 0xffffu)), a0);
            a1 = fmaf(m2, bf2f((unsigned short)(v2 >> 16)), a1);
            a0 = fmaf(m3, bf2f((unsigned short)(v3 & 0xffffu)), a0);
            a1 = fmaf(m3, bf2f((unsigned short)(v3 >> 16)), a1);
        }
    }
    float inv = 1.0f / fmaxf((float)n, 1.0f);
    unsigned outv = pack2(a0 * inv, a1 * inv);
    *(unsigned*)(hist + (size_t)wave * 128 + lane * 2) = outv;
}

// ============================================================================
// Kernel 4: user encoder via MFMA.
// ============================================================================
#define XS_U 216   // X stride bf16 (192 + 24 pad)

__global__ __launch_bounds__(256, 2)
void user_mfma_kernel(const float* __restrict__ gcn_user,
                      const unsigned short* __restrict__ hist,
                      const unsigned short* __restrict__ W1ut,
                      const unsigned short* __restrict__ W2ut,
                      const float* __restrict__ bu1, const float* __restrict__ bu2,
                      const int* __restrict__ users,
                      float* __restrict__ out)
{
    __shared__ unsigned short Xs[64 * XS_U];
    __shared__ unsigned short Hs[64 * HS];
    __shared__ float ssq[64][4];

    const int t  = threadIdx.x;
    const int w  = t >> 6;
    const int l  = t & 63;
    const int lo = l & 15;
    const int hi = l >> 4;
    const int r0 = blockIdx.x * 64;

    // ---- stage X: cols 0-63 gcn_user (f32->bf16), 64-191 hist (bf16 copy) ----
    {
        const int row = t >> 2, q = t & 3;
        int rr = r0 + row;
        int u = users[rr < NUSERS ? rr : (NUSERS - 1)];
        const float4* g = (const float4*)(gcn_user + (size_t)u * 64 + q * 16);
        unsigned* dst = (unsigned*)((char*)Xs + row * (XS_U * 2) + q * 32);
        #pragma unroll
        for (int k = 0; k < 4; ++k) {
            float4 v = g[k];
            dst[2 * k]     = pack2(v.x, v.y);
            dst[2 * k + 1] = pack2(v.z, v.w);
        }
        const uint4* hp = (const uint4*)(hist + (size_t)u * 128 + q * 32);
        uint4* hd = (uint4*)((char*)Xs + row * (XS_U * 2) + 128 + q * 64);
        #pragma unroll
        for (int k = 0; k < 4; ++k) hd[k] = hp[k];
    }

    // ---- W1u fragments: 4 coltiles x 6 ktiles ----
    bf16x8 w1f[4][6];
    #pragma unroll
    for (int ct = 0; ct < 4; ++ct)
        #pragma unroll
        for (int kt = 0; kt < 6; ++kt) {
            int n = 64 * w + ct * 16 + lo;
            w1f[ct][kt] = *(const bf16x8*)(W1ut + n * 192 + kt * 32 + hi * 8);
        }

    __syncthreads();

    // ---- layer 1 ----
    f32x4 acc1[4][4];
    #pragma unroll
    for (int rt = 0; rt < 4; ++rt)
        #pragma unroll
        for (int ct = 0; ct < 4; ++ct)
            acc1[rt][ct] = (f32x4)(0.0f);

    #pragma unroll
    for (int rt = 0; rt < 4; ++rt) {
        #pragma unroll
        for (int kt = 0; kt < 6; ++kt) {
            bf16x8 a = *(const bf16x8*)((char*)Xs + (rt * 16 + lo) * (XS_U * 2) + kt * 64 + hi * 16);
            #pragma unroll
            for (int ct = 0; ct < 4; ++ct)
                acc1[rt][ct] = __builtin_amdgcn_mfma_f32_16x16x32_bf16(a, w1f[ct][kt], acc1[rt][ct], 0, 0, 0);
        }
    }

    {
        float b1v[4];
        #pragma unroll
        for (int ct = 0; ct < 4; ++ct) b1v[ct] = bu1[64 * w + ct * 16 + lo];
        #pragma unroll
        for (int rt = 0; rt < 4; ++rt)
            #pragma unroll
            for (int ct = 0; ct < 4; ++ct)
                #pragma unroll
                for (int r = 0; r < 4; ++r) {
                    float h = fmaxf(acc1[rt][ct][r] + b1v[ct], 0.0f);
                    Hs[(rt * 16 + 4 * hi + r) * HS + 64 * w + ct * 16 + lo] = f2bf(h);
                }
    }

    // ---- W2u fragments loaded after layer 1 (keeps VGPR peak down) ----
    bf16x8 w2f[2][8];
    #pragma unroll
    for (int ct = 0; ct < 2; ++ct)
        #pragma unroll
        for (int kt = 0; kt < 8; ++kt) {
            int n = 32 * w + ct * 16 + lo;
            w2f[ct][kt] = *(const bf16x8*)(W2ut + n * 256 + kt * 32 + hi * 8);
        }
    __syncthreads();

    // ---- layer 2 ----
    f32x4 acc2[4][2];
    #pragma unroll
    for (int rt = 0; rt < 4; ++rt) {
        acc2[rt][0] = (f32x4)(0.0f);
        acc2[rt][1] = (f32x4)(0.0f);
    }
    #pragma unroll
    for (int rt = 0; rt < 4; ++rt) {
        #pragma unroll
        for (int kt = 0; kt < 8; ++kt) {
            bf16x8 a = *(const bf16x8*)((char*)Hs + (rt * 16 + lo) * (HS * 2) + kt * 64 + hi * 16);
            #pragma unroll
            for (int ct = 0; ct < 2; ++ct)
                acc2[rt][ct] = __builtin_amdgcn_mfma_f32_16x16x32_bf16(a, w2f[ct][kt], acc2[rt][ct], 0, 0, 0);
        }
    }

    // ---- bias, L2 norm, f32 store ----
    float b2v[2];
    b2v[0] = bu2[32 * w + lo];
    b2v[1] = bu2[32 * w + 16 + lo];
    #pragma unroll
    for (int rt = 0; rt < 4; ++rt)
        #pragma unroll
        for (int r = 0; r < 4; ++r) {
            float v0 = acc2[rt][0][r] + b2v[0];
            float v1 = acc2[rt][1][r] + b2v[1];
            acc2[rt][0][r] = v0;
            acc2[rt][1][r] = v1;
            float p = v0 * v0 + v1 * v1;
            p += __shfl_xor(p, 1);
            p += __shfl_xor(p, 2);
            p += __shfl_xor(p, 4);
            p += __shfl_xor(p, 8);
            if (lo == 0) ssq[rt * 16 + 4 * hi + r][w] = p;
        }
    __syncthreads();

    #pragma unroll
    for (int rt = 0; rt < 4; ++rt)
        #pragma unroll
        for (int r = 0; r < 4; ++r) {
            int row = rt * 16 + 4 * hi + r;
            if (r0 + row >= NUSERS) continue;
            float4 s4 = *(const float4*)&ssq[row][0];
            float tot = s4.x + s4.y + s4.z + s4.w;
            float sc = 1.0f / fmaxf(sqrtf(tot), 1e-12f);
            float* dst = out + (size_t)(r0 + row) * 128 + 32 * w + lo;
            dst[0]  = acc2[rt][0][r] * sc;
            dst[16] = acc2[rt][1][r] * sc;
        }
}

// ============================================================================
extern "C" void kernel_launch(void* const* d_in, const int* in_sizes, int n_in,
                              void* d_out, int out_size, void* d_ws, size_t ws_size,
                              hipStream_t stream)
{
    const float* item_feat = (const float*)d_in[0];
    const float* gcn_item  = (const float*)d_in[1];
    const float* gcn_user  = (const float*)d_in[2];
    const float* Wi1 = (const float*)d_in[3];
    const float* bi1 = (const float*)d_in[4];
    const float* Wi2 = (const float*)d_in[5];
    const float* bi2 = (const float*)d_in[6];
    const float* Wu1 = (const float*)d_in[7];
    const float* bu1 = (const float*)d_in[8];
    const float* Wu2 = (const float*)d_in[9];
    const float* bu2 = (const float*)d_in[10];
    const int* item_idx = (const int*)d_in[11];
    const int* seg_ids  = (const int*)d_in[12];
    const int* users    = (const int*)d_in[13];
    float* out = (float*)d_out;

    // workspace layout
    char* ws = (char*)d_ws;
    unsigned short* item_emb = (unsigned short*)ws;                         // 51.2 MB
    unsigned short* hist = (unsigned short*)(ws + (size_t)NITEMS * 256);    // 25.6 MB
    size_t off = (size_t)NITEMS * 256 + (size_t)NUSERS * 256;
    int* start = (int*)(ws + off);                                          // 400 KB
    off += ((size_t)(NUSERS + 1) * 4 + 255) & ~(size_t)255;
    unsigned short* W1t  = (unsigned short*)(ws + off); off += 256 * 96 * 2;
    unsigned short* W2t  = (unsigned short*)(ws + off); off += 128 * 256 * 2;
    unsigned short* W1ut = (unsigned short*)(ws + off); off += 256 * 192 * 2;
    unsigned short* W2ut = (unsigned short*)(ws + off);

    hipLaunchKernelGGL(preconv_kernel, dim3(544), dim3(256), 0, stream,
                       Wi1, Wi2, Wu1, Wu2, W1t, W2t, W1ut, W2ut);

    hipLaunchKernelGGL(seg_bounds_kernel, dim3((NUSERS + 1 + 255) / 256), dim3(256), 0, stream,
                       seg_ids, start);

    hipLaunchKernelGGL(item_mfma_kernel, dim3(NITEMS / 64), dim3(256), 0, stream,
                       item_feat, gcn_item, W1t, W2t, bi1, bi2, item_emb);

    hipLaunchKernelGGL(seg_mean_kernel, dim3(NUSERS / 4), dim3(256), 0, stream,
                       item_idx, start, item_emb, hist);

    hipLaunchKernelGGL(user_mfma_kernel, dim3((NUSERS + 63) / 64), dim3(256), 0, stream,
                       gcn_user, hist, W1ut, W2ut, bu1, bu2, users, out);
}

// Round 7
// 331.621 us; speedup vs baseline: 23.6090x; 1.0916x over previous
//
#include <hip/hip_runtime.h>
#include <hip/hip_bf16.h>
#include <cstdint>
#include <cstddef>

#define NITEMS 200000
#define NUSERS 100000
#define NINTER 2000000

typedef __attribute__((ext_vector_type(8))) short bf16x8;
typedef __attribute__((ext_vector_type(4))) float f32x4;

// ---- bf16 helpers (bit-level, RNE) ----
__device__ __forceinline__ unsigned short f2bf(float f) {
    union { float f; unsigned u; } v; v.f = f;
    unsigned r = v.u + 0x7fffu + ((v.u >> 16) & 1u);
    return (unsigned short)(r >> 16);
}
__device__ __forceinline__ float bf2f(unsigned short h) {
    union { unsigned u; float f; } v; v.u = ((unsigned)h) << 16;
    return v.f;
}
__device__ __forceinline__ unsigned pack2(float a, float b) {
    return (unsigned)f2bf(a) | ((unsigned)f2bf(b) << 16);
}

// ============================================================================
// Kernel 0: transpose + convert weights to bf16 [N][K] (MFMA A/B frag = 16B load)
// ============================================================================
__global__ void preconv_kernel(const float* __restrict__ Wi1, const float* __restrict__ Wi2,
                               const float* __restrict__ Wu1, const float* __restrict__ Wu2,
                               unsigned short* __restrict__ W1t, unsigned short* __restrict__ W2t,
                               unsigned short* __restrict__ W1ut, unsigned short* __restrict__ W2ut)
{
    int t = blockIdx.x * 256 + threadIdx.x;
    if (t < 256 * 96) {
        int n = t / 96, k = t % 96;
        W1t[t] = (k < 66) ? f2bf(Wi1[k * 256 + n]) : (unsigned short)0;
        return;
    }
    t -= 256 * 96;
    if (t < 128 * 256) {
        int n = t / 256, k = t % 256;
        W2t[t] = f2bf(Wi2[k * 128 + n]);
        return;
    }
    t -= 128 * 256;
    if (t < 256 * 192) {
        int n = t / 192, k = t % 192;
        W1ut[t] = f2bf(Wu1[k * 256 + n]);
        return;
    }
    t -= 256 * 192;
    if (t < 128 * 256) {
        int n = t / 256, k = t % 256;
        W2ut[t] = f2bf(Wu2[k * 128 + n]);
    }
}

#define HSI 264    // H LDS stride elems (528B: 16B-mult, 2-way-class reads)
#define XS  104    // item X stride elems (208B)
#define XSU 200    // user X stride elems (400B)

// ============================================================================
// Kernel 1: item encoder. Persistent blocks (grid=512), swapped-operand MFMA:
//   D = W^T-frag (A) x X^T-frag (B)  ->  lane holds 4 CONSECUTIVE output cols
//   of one row (col=l&15 -> row-of-tile, 4*hi+reg -> out col). Packed b64
//   H-writes, dwordx2 C-stores. Weights/biases in regs for whole kernel.
// ============================================================================
__global__ __launch_bounds__(256, 2)
void item_mfma_kernel(const float* __restrict__ item_feat,
                      const float* __restrict__ gcn_item,
                      const unsigned short* __restrict__ W1t,
                      const unsigned short* __restrict__ W2t,
                      const float* __restrict__ bi1, const float* __restrict__ bi2,
                      unsigned short* __restrict__ item_emb)
{
    __shared__ unsigned short Xs[64 * XS];
    __shared__ unsigned short Hs[64 * HSI];
    __shared__ float ssq[64][4];

    const int t  = threadIdx.x;
    const int w  = t >> 6;
    const int l  = t & 63;
    const int lo = l & 15;
    const int hi = l >> 4;

    // ---- persistent weight fragments + biases ----
    bf16x8 w1f[4][3];
    #pragma unroll
    for (int mt = 0; mt < 4; ++mt)
        #pragma unroll
        for (int kt = 0; kt < 3; ++kt)
            w1f[mt][kt] = *(const bf16x8*)(W1t + (64 * w + mt * 16 + lo) * 96 + kt * 32 + hi * 8);
    bf16x8 w2f[2][8];
    #pragma unroll
    for (int ct = 0; ct < 2; ++ct)
        #pragma unroll
        for (int kt = 0; kt < 8; ++kt)
            w2f[ct][kt] = *(const bf16x8*)(W2t + (32 * w + ct * 16 + lo) * 256 + kt * 32 + hi * 8);
    f32x4 b1v[4];
    #pragma unroll
    for (int mt = 0; mt < 4; ++mt) b1v[mt] = *(const f32x4*)(bi1 + 64 * w + mt * 16 + 4 * hi);
    f32x4 b2v[2];
    #pragma unroll
    for (int ct = 0; ct < 2; ++ct) b2v[ct] = *(const f32x4*)(bi2 + 32 * w + ct * 16 + 4 * hi);

    // ---- zero pad X cols 66..95 once (never overwritten) ----
    if (t < 64) {
        unsigned* z = (unsigned*)((char*)Xs + t * (XS * 2) + 132);
        #pragma unroll
        for (int k = 0; k < 15; ++k) z[k] = 0u;
    }

    for (int tile = blockIdx.x; tile < NITEMS / 64; tile += gridDim.x) {
        const size_t i0 = (size_t)tile * 64;

        // ---- stage X: row = t>>2, 4 threads/row ----
        {
            const int row = t >> 2, q = t & 3;
            const float4* g = (const float4*)(gcn_item + (i0 + row) * 64 + q * 16);
            unsigned* dst = (unsigned*)((char*)Xs + row * (XS * 2) + 4 + q * 32);
            #pragma unroll
            for (int k = 0; k < 4; ++k) {
                float4 v = g[k];
                dst[2 * k]     = pack2(v.x, v.y);
                dst[2 * k + 1] = pack2(v.z, v.w);
            }
            if (q == 0) {
                float2 f = *(const float2*)(item_feat + (i0 + row) * 2);
                *(unsigned*)((char*)Xs + row * (XS * 2)) = pack2(f.x, f.y);
            }
        }
        __syncthreads();   // A: stage visible; prev tile fully consumed

        // ---- layer 1: D = W1^T x X^T ----
        f32x4 acc1[4][4];
        #pragma unroll
        for (int mt = 0; mt < 4; ++mt)
            #pragma unroll
            for (int nt = 0; nt < 4; ++nt)
                acc1[mt][nt] = (f32x4)(0.0f);
        #pragma unroll
        for (int nt = 0; nt < 4; ++nt)
            #pragma unroll
            for (int kt = 0; kt < 3; ++kt) {
                bf16x8 b = *(const bf16x8*)((char*)Xs + (nt * 16 + lo) * (XS * 2) + kt * 64 + hi * 16);
                #pragma unroll
                for (int mt = 0; mt < 4; ++mt)
                    acc1[mt][nt] = __builtin_amdgcn_mfma_f32_16x16x32_bf16(w1f[mt][kt], b, acc1[mt][nt], 0, 0, 0);
            }

        // ---- bias+relu+pack -> b64 H writes: H[row n][cols 64w+16mt+4hi..+3] ----
        #pragma unroll
        for (int mt = 0; mt < 4; ++mt)
            #pragma unroll
            for (int nt = 0; nt < 4; ++nt) {
                float v0 = fmaxf(acc1[mt][nt][0] + b1v[mt][0], 0.0f);
                float v1 = fmaxf(acc1[mt][nt][1] + b1v[mt][1], 0.0f);
                float v2 = fmaxf(acc1[mt][nt][2] + b1v[mt][2], 0.0f);
                float v3 = fmaxf(acc1[mt][nt][3] + b1v[mt][3], 0.0f);
                uint2 pk = make_uint2(pack2(v0, v1), pack2(v2, v3));
                *(uint2*)((char*)Hs + (nt * 16 + lo) * (HSI * 2) + (64 * w + mt * 16 + 4 * hi) * 2) = pk;
            }
        __syncthreads();   // B: H ready

        // ---- layer 2: D = W2^T x H^T ----
        f32x4 acc2[4][2];
        #pragma unroll
        for (int nt = 0; nt < 4; ++nt) { acc2[nt][0] = (f32x4)(0.0f); acc2[nt][1] = (f32x4)(0.0f); }
        #pragma unroll
        for (int nt = 0; nt < 4; ++nt)
            #pragma unroll
            for (int kt = 0; kt < 8; ++kt) {
                bf16x8 b = *(const bf16x8*)((char*)Hs + (nt * 16 + lo) * (HSI * 2) + kt * 64 + hi * 16);
                #pragma unroll
                for (int ct = 0; ct < 2; ++ct)
                    acc2[nt][ct] = __builtin_amdgcn_mfma_f32_16x16x32_bf16(w2f[ct][kt], b, acc2[nt][ct], 0, 0, 0);
            }

        // ---- bias + row sum-of-squares (2 shuffles + cross-wave LDS) ----
        #pragma unroll
        for (int nt = 0; nt < 4; ++nt) {
            float p = 0.0f;
            #pragma unroll
            for (int ct = 0; ct < 2; ++ct)
                #pragma unroll
                for (int r = 0; r < 4; ++r) {
                    float v = acc2[nt][ct][r] + b2v[ct][r];
                    acc2[nt][ct][r] = v;
                    p = fmaf(v, v, p);
                }
            p += __shfl_xor(p, 16);
            p += __shfl_xor(p, 32);
            if (hi == 0) ssq[nt * 16 + lo][w] = p;
        }
        __syncthreads();   // C: ssq ready

        #pragma unroll
        for (int nt = 0; nt < 4; ++nt) {
            float4 s4 = *(const float4*)&ssq[nt * 16 + lo][0];
            float sc = 1.0f / fmaxf(sqrtf(s4.x + s4.y + s4.z + s4.w), 1e-12f);
            #pragma unroll
            for (int ct = 0; ct < 2; ++ct) {
                uint2 pk = make_uint2(pack2(acc2[nt][ct][0] * sc, acc2[nt][ct][1] * sc),
                                      pack2(acc2[nt][ct][2] * sc, acc2[nt][ct][3] * sc));
                *(uint2*)(item_emb + (i0 + nt * 16 + lo) * 128 + 32 * w + ct * 16 + 4 * hi) = pk;
            }
        }
    }
}

// ============================================================================
// Kernel 2: segment offsets (binary search over sorted seg_ids)
// ============================================================================
__global__ void seg_bounds_kernel(const int* __restrict__ seg, int* __restrict__ start)
{
    int u = blockIdx.x * 256 + threadIdx.x;
    if (u > NUSERS) return;
    int lo = 0, hi = NINTER;
    while (lo < hi) {
        int m = (lo + hi) >> 1;
        if (seg[m] < u) lo = m + 1; else hi = m;
    }
    start[u] = lo;
}

// ============================================================================
// Kernel 3: segment mean — software-pipelined gather (x4 + idx prefetch)
// ============================================================================
__global__ __launch_bounds__(256)
void seg_mean_kernel(const int* __restrict__ item_idx,
                     const int* __restrict__ start,
                     const unsigned short* __restrict__ item_emb,
                     unsigned short* __restrict__ hist)
{
    int gid  = blockIdx.x * 256 + threadIdx.x;
    int wave = gid >> 6;
    int lane = gid & 63;
    if (wave >= NUSERS) return;

    int s = start[wave], e = start[wave + 1];
    int n = e - s;
    float a0 = 0.0f, a1 = 0.0f;

    if (n > 0) {
        const int elast = e - 1;
        int i0 = item_idx[s];
        int i1 = item_idx[min(s + 1, elast)];
        int i2 = item_idx[min(s + 2, elast)];
        int i3 = item_idx[min(s + 3, elast)];
        for (int r = s; r < e; r += 4) {
            const int j0 = i0, j1 = i1, j2 = i2, j3 = i3;
            int rn = r + 4;
            if (rn < e) {
                i0 = item_idx[rn];
                i1 = item_idx[min(rn + 1, elast)];
                i2 = item_idx[min(rn + 2, elast)];
                i3 = item_idx[min(rn + 3, elast)];
            }
            unsigned v0 = *(const unsigned*)(item_emb + (size_t)j0 * 128 + lane * 2);
            unsigned v1 = *(const unsigned*)(item_emb + (size_t)j1 * 128 + lane * 2);
            unsigned v2 = *(const unsigned*)(item_emb + (size_t)j2 * 128 + lane * 2);
            unsigned v3 = *(const unsigned*)(item_emb + (size_t)j3 * 128 + lane * 2);
            const float m1 = (r + 1 < e) ? 1.0f : 0.0f;
            const float m2 = (r + 2 < e) ? 1.0f : 0.0f;
            const float m3 = (r + 3 < e) ? 1.0f : 0.0f;
            a0 += bf2f((unsigned short)(v0 & 0xffffu));
            a1 += bf2f((unsigned short)(v0 >> 16));
            a0 = fmaf(m1, bf2f((unsigned short)(v1 & 0xffffu)), a0);
            a1 = fmaf(m1, bf2f((unsigned short)(v1 >> 16)), a1);
            a0 = fmaf(m2, bf2f((unsigned short)(v2 & 0xffffu)), a0);
            a1 = fmaf(m2, bf2f((unsigned short)(v2 >> 16)), a1);
            a0 = fmaf(m3, bf2f((unsigned short)(v3 & 0xffffu)), a0);
            a1 = fmaf(m3, bf2f((unsigned short)(v3 >> 16)), a1);
        }
    }
    float inv = 1.0f / fmaxf((float)n, 1.0f);
    unsigned outv = pack2(a0 * inv, a1 * inv);
    *(unsigned*)(hist + (size_t)wave * 128 + lane * 2) = outv;
}

// ============================================================================
// Kernel 4: user encoder. Same persistent swapped-operand structure.
// W1u (96 VGPR) persistent; W2u re-loaded per tile (L2-hot) to cap VGPR peak.
// ============================================================================
__global__ __launch_bounds__(256, 2)
void user_mfma_kernel(const float* __restrict__ gcn_user,
                      const unsigned short* __restrict__ hist,
                      const unsigned short* __restrict__ W1ut,
                      const unsigned short* __restrict__ W2ut,
                      const float* __restrict__ bu1, const float* __restrict__ bu2,
                      const int* __restrict__ users,
                      float* __restrict__ out)
{
    __shared__ unsigned short Xs[64 * XSU];
    __shared__ unsigned short Hs[64 * HSI];
    __shared__ float ssq[64][4];

    const int t  = threadIdx.x;
    const int w  = t >> 6;
    const int l  = t & 63;
    const int lo = l & 15;
    const int hi = l >> 4;
    const int NT = (NUSERS + 63) / 64;

    bf16x8 w1f[4][6];
    #pragma unroll
    for (int mt = 0; mt < 4; ++mt)
        #pragma unroll
        for (int kt = 0; kt < 6; ++kt)
            w1f[mt][kt] = *(const bf16x8*)(W1ut + (64 * w + mt * 16 + lo) * 192 + kt * 32 + hi * 8);
    f32x4 b1v[4];
    #pragma unroll
    for (int mt = 0; mt < 4; ++mt) b1v[mt] = *(const f32x4*)(bu1 + 64 * w + mt * 16 + 4 * hi);
    f32x4 b2v[2];
    #pragma unroll
    for (int ct = 0; ct < 2; ++ct) b2v[ct] = *(const f32x4*)(bu2 + 32 * w + ct * 16 + 4 * hi);

    for (int tile = blockIdx.x; tile < NT; tile += gridDim.x) {
        const int r0 = tile * 64;

        // ---- stage X: cols 0-63 gcn (f32->bf16), 64-191 hist copy ----
        {
            const int row = t >> 2, q = t & 3;
            int rr = r0 + row;
            int u = users[rr < NUSERS ? rr : (NUSERS - 1)];
            const float4* g = (const float4*)(gcn_user + (size_t)u * 64 + q * 16);
            unsigned* dst = (unsigned*)((char*)Xs + row * (XSU * 2) + q * 32);
            #pragma unroll
            for (int k = 0; k < 4; ++k) {
                float4 v = g[k];
                dst[2 * k]     = pack2(v.x, v.y);
                dst[2 * k + 1] = pack2(v.z, v.w);
            }
            const uint4* hp = (const uint4*)(hist + (size_t)u * 128 + q * 32);
            uint4* hd = (uint4*)((char*)Xs + row * (XSU * 2) + 128 + q * 64);
            #pragma unroll
            for (int k = 0; k < 4; ++k) hd[k] = hp[k];
        }
        __syncthreads();   // A

        // ---- layer 1 ----
        f32x4 acc1[4][4];
        #pragma unroll
        for (int mt = 0; mt < 4; ++mt)
            #pragma unroll
            for (int nt = 0; nt < 4; ++nt)
                acc1[mt][nt] = (f32x4)(0.0f);
        #pragma unroll
        for (int nt = 0; nt < 4; ++nt)
            #pragma unroll
            for (int kt = 0; kt < 6; ++kt) {
                bf16x8 b = *(const bf16x8*)((char*)Xs + (nt * 16 + lo) * (XSU * 2) + kt * 64 + hi * 16);
                #pragma unroll
                for (int mt = 0; mt < 4; ++mt)
                    acc1[mt][nt] = __builtin_amdgcn_mfma_f32_16x16x32_bf16(w1f[mt][kt], b, acc1[mt][nt], 0, 0, 0);
            }

        #pragma unroll
        for (int mt = 0; mt < 4; ++mt)
            #pragma unroll
            for (int nt = 0; nt < 4; ++nt) {
                float v0 = fmaxf(acc1[mt][nt][0] + b1v[mt][0], 0.0f);
                float v1 = fmaxf(acc1[mt][nt][1] + b1v[mt][1], 0.0f);
                float v2 = fmaxf(acc1[mt][nt][2] + b1v[mt][2], 0.0f);
                float v3 = fmaxf(acc1[mt][nt][3] + b1v[mt][3], 0.0f);
                uint2 pk = make_uint2(pack2(v0, v1), pack2(v2, v3));
                *(uint2*)((char*)Hs + (nt * 16 + lo) * (HSI * 2) + (64 * w + mt * 16 + 4 * hi) * 2) = pk;
            }

        // ---- W2u frags per tile (acc1 dead; keeps VGPR peak < 256) ----
        bf16x8 w2f[2][8];
        #pragma unroll
        for (int ct = 0; ct < 2; ++ct)
            #pragma unroll
            for (int kt = 0; kt < 8; ++kt)
                w2f[ct][kt] = *(const bf16x8*)(W2ut + (32 * w + ct * 16 + lo) * 256 + kt * 32 + hi * 8);
        __syncthreads();   // B

        // ---- layer 2 ----
        f32x4 acc2[4][2];
        #pragma unroll
        for (int nt = 0; nt < 4; ++nt) { acc2[nt][0] = (f32x4)(0.0f); acc2[nt][1] = (f32x4)(0.0f); }
        #pragma unroll
        for (int nt = 0; nt < 4; ++nt)
            #pragma unroll
            for (int kt = 0; kt < 8; ++kt) {
                bf16x8 b = *(const bf16x8*)((char*)Hs + (nt * 16 + lo) * (HSI * 2) + kt * 64 + hi * 16);
                #pragma unroll
                for (int ct = 0; ct < 2; ++ct)
                    acc2[nt][ct] = __builtin_amdgcn_mfma_f32_16x16x32_bf16(w2f[ct][kt], b, acc2[nt][ct], 0, 0, 0);
            }

        #pragma unroll
        for (int nt = 0; nt < 4; ++nt) {
            float p = 0.0f;
            #pragma unroll
            for (int ct = 0; ct < 2; ++ct)
                #pragma unroll
                for (int r = 0; r < 4; ++r) {
                    float v = acc2[nt][ct][r] + b2v[ct][r];
                    acc2[nt][ct][r] = v;
                    p = fmaf(v, v, p);
                }
            p += __shfl_xor(p, 16);
            p += __shfl_xor(p, 32);
            if (hi == 0) ssq[nt * 16 + lo][w] = p;
        }
        __syncthreads();   // C

        #pragma unroll
        for (int nt = 0; nt < 4; ++nt) {
            int row = r0 + nt * 16 + lo;
            float4 s4 = *(const float4*)&ssq[nt * 16 + lo][0];
            float sc = 1.0f / fmaxf(sqrtf(s4.x + s4.y + s4.z + s4.w), 1e-12f);
            if (row < NUSERS) {
                #pragma unroll
                for (int ct = 0; ct < 2; ++ct) {
                    float4 st = make_float4(acc2[nt][ct][0] * sc, acc2[nt][ct][1] * sc,
                                            acc2[nt][ct][2] * sc, acc2[nt][ct][3] * sc);
                    *(float4*)(out + (size_t)row * 128 + 32 * w + ct * 16 + 4 * hi) = st;
                }
            }
        }
    }
}

// ============================================================================
extern "C" void kernel_launch(void* const* d_in, const int* in_sizes, int n_in,
                              void* d_out, int out_size, void* d_ws, size_t ws_size,
                              hipStream_t stream)
{
    const float* item_feat = (const float*)d_in[0];
    const float* gcn_item  = (const float*)d_in[1];
    const float* gcn_user  = (const float*)d_in[2];
    const float* Wi1 = (const float*)d_in[3];
    const float* bi1 = (const float*)d_in[4];
    const float* Wi2 = (const float*)d_in[5];
    const float* bi2 = (const float*)d_in[6];
    const float* Wu1 = (const float*)d_in[7];
    const float* bu1 = (const float*)d_in[8];
    const float* Wu2 = (const float*)d_in[9];
    const float* bu2 = (const float*)d_in[10];
    const int* item_idx = (const int*)d_in[11];
    const int* seg_ids  = (const int*)d_in[12];
    const int* users    = (const int*)d_in[13];
    float* out = (float*)d_out;

    // workspace layout
    char* ws = (char*)d_ws;
    unsigned short* item_emb = (unsigned short*)ws;                         // 51.2 MB
    unsigned short* hist = (unsigned short*)(ws + (size_t)NITEMS * 256);    // 25.6 MB
    size_t off = (size_t)NITEMS * 256 + (size_t)NUSERS * 256;
    int* start = (int*)(ws + off);                                          // 400 KB
    off += ((size_t)(NUSERS + 1) * 4 + 255) & ~(size_t)255;
    unsigned short* W1t  = (unsigned short*)(ws + off); off += 256 * 96 * 2;
    unsigned short* W2t  = (unsigned short*)(ws + off); off += 128 * 256 * 2;
    unsigned short* W1ut = (unsigned short*)(ws + off); off += 256 * 192 * 2;
    unsigned short* W2ut = (unsigned short*)(ws + off);

    hipLaunchKernelGGL(preconv_kernel, dim3(544), dim3(256), 0, stream,
                       Wi1, Wi2, Wu1, Wu2, W1t, W2t, W1ut, W2ut);

    hipLaunchKernelGGL(seg_bounds_kernel, dim3((NUSERS + 1 + 255) / 256), dim3(256), 0, stream,
                       seg_ids, start);

    hipLaunchKernelGGL(item_mfma_kernel, dim3(512), dim3(256), 0, stream,
                       item_feat, gcn_item, W1t, W2t, bi1, bi2, item_emb);

    hipLaunchKernelGGL(seg_mean_kernel, dim3(NUSERS / 4), dim3(256), 0, stream,
                       item_idx, start, item_emb, hist);

    hipLaunchKernelGGL(user_mfma_kernel, dim3(512), dim3(256), 0, stream,
                       gcn_user, hist, W1ut, W2ut, bu1, bu2, users, out);
}

// Round 10
// 315.336 us; speedup vs baseline: 24.8282x; 1.0516x over previous
//
#include <hip/hip_runtime.h>
#include <hip/hip_bf16.h>
#include <cstdint>
#include <cstddef>

#define NITEMS 200000
#define NUSERS 100000
#define NINTER 2000000

typedef __attribute__((ext_vector_type(8))) short bf16x8;
typedef __attribute__((ext_vector_type(4))) float f32x4;

// ---- bf16 helpers (bit-level, RNE) ----
__device__ __forceinline__ unsigned short f2bf(float f) {
    union { float f; unsigned u; } v; v.f = f;
    unsigned r = v.u + 0x7fffu + ((v.u >> 16) & 1u);
    return (unsigned short)(r >> 16);
}
__device__ __forceinline__ float bf2f(unsigned short h) {
    union { unsigned u; float f; } v; v.u = ((unsigned)h) << 16;
    return v.f;
}
__device__ __forceinline__ unsigned pack2(float a, float b) {
    return (unsigned)f2bf(a) | ((unsigned)f2bf(b) << 16);
}

// ============================================================================
// Kernel 0: prep = weight transpose/convert (bf16 [N][K]) + segment offsets.
// Fused to save a launch gap; the two halves are independent.
// ============================================================================
__global__ void prep_kernel(const float* __restrict__ Wi1, const float* __restrict__ Wi2,
                            const float* __restrict__ Wu1, const float* __restrict__ Wu2,
                            const int* __restrict__ seg,
                            unsigned short* __restrict__ W1t, unsigned short* __restrict__ W2t,
                            unsigned short* __restrict__ W1ut, unsigned short* __restrict__ W2ut,
                            int* __restrict__ start)
{
    int t = blockIdx.x * 256 + threadIdx.x;
    if (t < 256 * 96) {
        int n = t / 96, k = t % 96;
        W1t[t] = (k < 66) ? f2bf(Wi1[k * 256 + n]) : (unsigned short)0;
        return;
    }
    t -= 256 * 96;
    if (t < 128 * 256) {
        int n = t / 256, k = t % 256;
        W2t[t] = f2bf(Wi2[k * 128 + n]);
        return;
    }
    t -= 128 * 256;
    if (t < 256 * 192) {
        int n = t / 192, k = t % 192;
        W1ut[t] = f2bf(Wu1[k * 256 + n]);
        return;
    }
    t -= 256 * 192;
    if (t < 128 * 256) {
        int n = t / 256, k = t % 256;
        W2ut[t] = f2bf(Wu2[k * 128 + n]);
        return;
    }
    t -= 128 * 256;
    if (t <= NUSERS) {
        int lo = 0, hi = NINTER;
        while (lo < hi) {
            int m = (lo + hi) >> 1;
            if (seg[m] < t) lo = m + 1; else hi = m;
        }
        start[t] = lo;
    }
}

#define HSI 264    // H LDS stride elems (528B: 16B-mult, conflict-light)
#define XS  104    // item X stride elems (208B)
#define XSU 200    // user X stride elems (400B)

// ============================================================================
// Kernel 1: item encoder. Persistent blocks (grid=512), swapped-operand MFMA
// (D = Wfrag x Xfrag -> lane holds 4 consecutive out cols of one row).
// Weight frags loaded per-K-slice INSIDE the loop (16/8 VGPR live) -> no spill.
// ============================================================================
__global__ __launch_bounds__(256, 2)
void item_mfma_kernel(const float* __restrict__ item_feat,
                      const float* __restrict__ gcn_item,
                      const unsigned short* __restrict__ W1t,
                      const unsigned short* __restrict__ W2t,
                      const float* __restrict__ bi1, const float* __restrict__ bi2,
                      unsigned short* __restrict__ item_emb)
{
    __shared__ unsigned short Xs[64 * XS];
    __shared__ unsigned short Hs[64 * HSI];
    __shared__ float ssq[64][4];

    const int t  = threadIdx.x;
    const int w  = t >> 6;
    const int l  = t & 63;
    const int lo = l & 15;
    const int hi = l >> 4;

    // ---- zero pad X cols 66..95 once (never overwritten) ----
    if (t < 64) {
        unsigned* z = (unsigned*)((char*)Xs + t * (XS * 2) + 132);
        #pragma unroll
        for (int k = 0; k < 15; ++k) z[k] = 0u;
    }

    for (int tile = blockIdx.x; tile < NITEMS / 64; tile += gridDim.x) {
        const size_t i0 = (size_t)tile * 64;

        // ---- stage X: row = t>>2, 4 threads/row ----
        {
            const int row = t >> 2, q = t & 3;
            const float4* g = (const float4*)(gcn_item + (i0 + row) * 64 + q * 16);
            unsigned* dst = (unsigned*)((char*)Xs + row * (XS * 2) + 4 + q * 32);
            #pragma unroll
            for (int k = 0; k < 4; ++k) {
                float4 v = g[k];
                dst[2 * k]     = pack2(v.x, v.y);
                dst[2 * k + 1] = pack2(v.z, v.w);
            }
            if (q == 0) {
                float2 f = *(const float2*)(item_feat + (i0 + row) * 2);
                *(unsigned*)((char*)Xs + row * (XS * 2)) = pack2(f.x, f.y);
            }
        }
        __syncthreads();   // A: stage visible; prev tile fully consumed

        // ---- layer 1: kt-outer, 4 weight frags live at a time ----
        f32x4 acc1[4][4];
        #pragma unroll
        for (int mt = 0; mt < 4; ++mt)
            #pragma unroll
            for (int nt = 0; nt < 4; ++nt)
                acc1[mt][nt] = (f32x4)(0.0f);
        #pragma unroll
        for (int kt = 0; kt < 3; ++kt) {
            bf16x8 wf[4];
            #pragma unroll
            for (int mt = 0; mt < 4; ++mt)
                wf[mt] = *(const bf16x8*)(W1t + (64 * w + mt * 16 + lo) * 96 + kt * 32 + hi * 8);
            #pragma unroll
            for (int nt = 0; nt < 4; ++nt) {
                bf16x8 b = *(const bf16x8*)((char*)Xs + (nt * 16 + lo) * (XS * 2) + kt * 64 + hi * 16);
                #pragma unroll
                for (int mt = 0; mt < 4; ++mt)
                    acc1[mt][nt] = __builtin_amdgcn_mfma_f32_16x16x32_bf16(wf[mt], b, acc1[mt][nt], 0, 0, 0);
            }
        }

        // ---- bias+relu+pack -> b64 H writes (bias loaded per mt, 4 regs) ----
        #pragma unroll
        for (int mt = 0; mt < 4; ++mt) {
            f32x4 b1 = *(const f32x4*)(bi1 + 64 * w + mt * 16 + 4 * hi);
            #pragma unroll
            for (int nt = 0; nt < 4; ++nt) {
                float v0 = fmaxf(acc1[mt][nt][0] + b1[0], 0.0f);
                float v1 = fmaxf(acc1[mt][nt][1] + b1[1], 0.0f);
                float v2 = fmaxf(acc1[mt][nt][2] + b1[2], 0.0f);
                float v3 = fmaxf(acc1[mt][nt][3] + b1[3], 0.0f);
                uint2 pk = make_uint2(pack2(v0, v1), pack2(v2, v3));
                *(uint2*)((char*)Hs + (nt * 16 + lo) * (HSI * 2) + (64 * w + mt * 16 + 4 * hi) * 2) = pk;
            }
        }
        __syncthreads();   // B: H ready

        // ---- layer 2: kt-outer, 2 weight frags live ----
        f32x4 acc2[4][2];
        #pragma unroll
        for (int nt = 0; nt < 4; ++nt) { acc2[nt][0] = (f32x4)(0.0f); acc2[nt][1] = (f32x4)(0.0f); }
        #pragma unroll
        for (int kt = 0; kt < 8; ++kt) {
            bf16x8 wf[2];
            #pragma unroll
            for (int ct = 0; ct < 2; ++ct)
                wf[ct] = *(const bf16x8*)(W2t + (32 * w + ct * 16 + lo) * 256 + kt * 32 + hi * 8);
            #pragma unroll
            for (int nt = 0; nt < 4; ++nt) {
                bf16x8 b = *(const bf16x8*)((char*)Hs + (nt * 16 + lo) * (HSI * 2) + kt * 64 + hi * 16);
                #pragma unroll
                for (int ct = 0; ct < 2; ++ct)
                    acc2[nt][ct] = __builtin_amdgcn_mfma_f32_16x16x32_bf16(wf[ct], b, acc2[nt][ct], 0, 0, 0);
            }
        }

        // ---- bias + row sum-of-squares (2 shuffles + cross-wave LDS) ----
        {
            f32x4 b2a = *(const f32x4*)(bi2 + 32 * w + 4 * hi);
            f32x4 b2b = *(const f32x4*)(bi2 + 32 * w + 16 + 4 * hi);
            #pragma unroll
            for (int nt = 0; nt < 4; ++nt) {
                float p = 0.0f;
                #pragma unroll
                for (int r = 0; r < 4; ++r) {
                    float v0 = acc2[nt][0][r] + b2a[r];
                    float v1 = acc2[nt][1][r] + b2b[r];
                    acc2[nt][0][r] = v0;
                    acc2[nt][1][r] = v1;
                    p = fmaf(v0, v0, fmaf(v1, v1, p));
                }
                p += __shfl_xor(p, 16);
                p += __shfl_xor(p, 32);
                if (hi == 0) ssq[nt * 16 + lo][w] = p;
            }
        }
        __syncthreads();   // C: ssq ready

        #pragma unroll
        for (int nt = 0; nt < 4; ++nt) {
            float4 s4 = *(const float4*)&ssq[nt * 16 + lo][0];
            float sc = 1.0f / fmaxf(sqrtf(s4.x + s4.y + s4.z + s4.w), 1e-12f);
            #pragma unroll
            for (int ct = 0; ct < 2; ++ct) {
                uint2 pk = make_uint2(pack2(acc2[nt][ct][0] * sc, acc2[nt][ct][1] * sc),
                                      pack2(acc2[nt][ct][2] * sc, acc2[nt][ct][3] * sc));
                *(uint2*)(item_emb + (i0 + nt * 16 + lo) * 128 + 32 * w + ct * 16 + 4 * hi) = pk;
            }
        }
    }
}

// ============================================================================
// Kernel 2: segment mean — software-pipelined gather (x4 + idx prefetch)
// ============================================================================
__global__ __launch_bounds__(256)
void seg_mean_kernel(const int* __restrict__ item_idx,
                     const int* __restrict__ start,
                     const unsigned short* __restrict__ item_emb,
                     unsigned short* __restrict__ hist)
{
    int gid  = blockIdx.x * 256 + threadIdx.x;
    int wave = gid >> 6;
    int lane = gid & 63;
    if (wave >= NUSERS) return;

    int s = start[wave], e = start[wave + 1];
    int n = e - s;
    float a0 = 0.0f, a1 = 0.0f;

    if (n > 0) {
        const int elast = e - 1;
        int i0 = item_idx[s];
        int i1 = item_idx[min(s + 1, elast)];
        int i2 = item_idx[min(s + 2, elast)];
        int i3 = item_idx[min(s + 3, elast)];
        for (int r = s; r < e; r += 4) {
            const int j0 = i0, j1 = i1, j2 = i2, j3 = i3;
            int rn = r + 4;
            if (rn < e) {
                i0 = item_idx[rn];
                i1 = item_idx[min(rn + 1, elast)];
                i2 = item_idx[min(rn + 2, elast)];
                i3 = item_idx[min(rn + 3, elast)];
            }
            unsigned v0 = *(const unsigned*)(item_emb + (size_t)j0 * 128 + lane * 2);
            unsigned v1 = *(const unsigned*)(item_emb + (size_t)j1 * 128 + lane * 2);
            unsigned v2 = *(const unsigned*)(item_emb + (size_t)j2 * 128 + lane * 2);
            unsigned v3 = *(const unsigned*)(item_emb + (size_t)j3 * 128 + lane * 2);
            const float m1 = (r + 1 < e) ? 1.0f : 0.0f;
            const float m2 = (r + 2 < e) ? 1.0f : 0.0f;
            const float m3 = (r + 3 < e) ? 1.0f : 0.0f;
            a0 += bf2f((unsigned short)(v0 & 0xffffu));
            a1 += bf2f((unsigned short)(v0 >> 16));
            a0 = fmaf(m1, bf2f((unsigned short)(v1 & 0xffffu)), a0);
            a1 = fmaf(m1, bf2f((unsigned short)(v1 >> 16)), a1);
            a0 = fmaf(m2, bf2f((unsigned short)(v2 & 0xffffu)), a0);
            a1 = fmaf(m2, bf2f((unsigned short)(v2 >> 16)), a1);
            a0 = fmaf(m3, bf2f((unsigned short)(v3 & 0xffffu)), a0);
            a1 = fmaf(m3, bf2f((unsigned short)(v3 >> 16)), a1);
        }
    }
    float inv = 1.0f / fmaxf((float)n, 1.0f);
    unsigned outv = pack2(a0 * inv, a1 * inv);
    *(unsigned*)(hist + (size_t)wave * 128 + lane * 2) = outv;
}

// ============================================================================
// Kernel 3: user encoder. Same structure; kt-scoped weight frags -> no spill.
// ============================================================================
__global__ __launch_bounds__(256, 2)
void user_mfma_kernel(const float* __restrict__ gcn_user,
                      const unsigned short* __restrict__ hist,
                      const unsigned short* __restrict__ W1ut,
                      const unsigned short* __restrict__ W2ut,
                      const float* __restrict__ bu1, const float* __restrict__ bu2,
                      const int* __restrict__ users,
                      float* __restrict__ out)
{
    __shared__ unsigned short Xs[64 * XSU];
    __shared__ unsigned short Hs[64 * HSI];
    __shared__ float ssq[64][4];

    const int t  = threadIdx.x;
    const int w  = t >> 6;
    const int l  = t & 63;
    const int lo = l & 15;
    const int hi = l >> 4;
    const int NT = (NUSERS + 63) / 64;

    for (int tile = blockIdx.x; tile < NT; tile += gridDim.x) {
        const int r0 = tile * 64;

        // ---- stage X: cols 0-63 gcn (f32->bf16), 64-191 hist copy ----
        {
            const int row = t >> 2, q = t & 3;
            int rr = r0 + row;
            int u = users[rr < NUSERS ? rr : (NUSERS - 1)];
            const float4* g = (const float4*)(gcn_user + (size_t)u * 64 + q * 16);
            unsigned* dst = (unsigned*)((char*)Xs + row * (XSU * 2) + q * 32);
            #pragma unroll
            for (int k = 0; k < 4; ++k) {
                float4 v = g[k];
                dst[2 * k]     = pack2(v.x, v.y);
                dst[2 * k + 1] = pack2(v.z, v.w);
            }
            const uint4* hp = (const uint4*)(hist + (size_t)u * 128 + q * 32);
            uint4* hd = (uint4*)((char*)Xs + row * (XSU * 2) + 128 + q * 64);
            #pragma unroll
            for (int k = 0; k < 4; ++k) hd[k] = hp[k];
        }
        __syncthreads();   // A

        // ---- layer 1: kt-outer (6), 4 weight frags live ----
        f32x4 acc1[4][4];
        #pragma unroll
        for (int mt = 0; mt < 4; ++mt)
            #pragma unroll
            for (int nt = 0; nt < 4; ++nt)
                acc1[mt][nt] = (f32x4)(0.0f);
        #pragma unroll
        for (int kt = 0; kt < 6; ++kt) {
            bf16x8 wf[4];
            #pragma unroll
            for (int mt = 0; mt < 4; ++mt)
                wf[mt] = *(const bf16x8*)(W1ut + (64 * w + mt * 16 + lo) * 192 + kt * 32 + hi * 8);
            #pragma unroll
            for (int nt = 0; nt < 4; ++nt) {
                bf16x8 b = *(const bf16x8*)((char*)Xs + (nt * 16 + lo) * (XSU * 2) + kt * 64 + hi * 16);
                #pragma unroll
                for (int mt = 0; mt < 4; ++mt)
                    acc1[mt][nt] = __builtin_amdgcn_mfma_f32_16x16x32_bf16(wf[mt], b, acc1[mt][nt], 0, 0, 0);
            }
        }

        #pragma unroll
        for (int mt = 0; mt < 4; ++mt) {
            f32x4 b1 = *(const f32x4*)(bu1 + 64 * w + mt * 16 + 4 * hi);
            #pragma unroll
            for (int nt = 0; nt < 4; ++nt) {
                float v0 = fmaxf(acc1[mt][nt][0] + b1[0], 0.0f);
                float v1 = fmaxf(acc1[mt][nt][1] + b1[1], 0.0f);
                float v2 = fmaxf(acc1[mt][nt][2] + b1[2], 0.0f);
                float v3 = fmaxf(acc1[mt][nt][3] + b1[3], 0.0f);
                uint2 pk = make_uint2(pack2(v0, v1), pack2(v2, v3));
                *(uint2*)((char*)Hs + (nt * 16 + lo) * (HSI * 2) + (64 * w + mt * 16 + 4 * hi) * 2) = pk;
            }
        }
        __syncthreads();   // B

        // ---- layer 2: kt-outer (8), 2 weight frags live ----
        f32x4 acc2[4][2];
        #pragma unroll
        for (int nt = 0; nt < 4; ++nt) { acc2[nt][0] = (f32x4)(0.0f); acc2[nt][1] = (f32x4)(0.0f); }
        #pragma unroll
        for (int kt = 0; kt < 8; ++kt) {
            bf16x8 wf[2];
            #pragma unroll
            for (int ct = 0; ct < 2; ++ct)
                wf[ct] = *(const bf16x8*)(W2ut + (32 * w + ct * 16 + lo) * 256 + kt * 32 + hi * 8);
            #pragma unroll
            for (int nt = 0; nt < 4; ++nt) {
                bf16x8 b = *(const bf16x8*)((char*)Hs + (nt * 16 + lo) * (HSI * 2) + kt * 64 + hi * 16);
                #pragma unroll
                for (int ct = 0; ct < 2; ++ct)
                    acc2[nt][ct] = __builtin_amdgcn_mfma_f32_16x16x32_bf16(wf[ct], b, acc2[nt][ct], 0, 0, 0);
            }
        }

        {
            f32x4 b2a = *(const f32x4*)(bu2 + 32 * w + 4 * hi);
            f32x4 b2b = *(const f32x4*)(bu2 + 32 * w + 16 + 4 * hi);
            #pragma unroll
            for (int nt = 0; nt < 4; ++nt) {
                float p = 0.0f;
                #pragma unroll
                for (int r = 0; r < 4; ++r) {
                    float v0 = acc2[nt][0][r] + b2a[r];
                    float v1 = acc2[nt][1][r] + b2b[r];
                    acc2[nt][0][r] = v0;
                    acc2[nt][1][r] = v1;
                    p = fmaf(v0, v0, fmaf(v1, v1, p));
                }
                p += __shfl_xor(p, 16);
                p += __shfl_xor(p, 32);
                if (hi == 0) ssq[nt * 16 + lo][w] = p;
            }
        }
        __syncthreads();   // C

        #pragma unroll
        for (int nt = 0; nt < 4; ++nt) {
            int row = r0 + nt * 16 + lo;
            float4 s4 = *(const float4*)&ssq[nt * 16 + lo][0];
            float sc = 1.0f / fmaxf(sqrtf(s4.x + s4.y + s4.z + s4.w), 1e-12f);
            if (row < NUSERS) {
                #pragma unroll
                for (int ct = 0; ct < 2; ++ct) {
                    float4 st = make_float4(acc2[nt][ct][0] * sc, acc2[nt][ct][1] * sc,
                                            acc2[nt][ct][2] * sc, acc2[nt][ct][3] * sc);
                    *(float4*)(out + (size_t)row * 128 + 32 * w + ct * 16 + 4 * hi) = st;
                }
            }
        }
    }
}

// ============================================================================
extern "C" void kernel_launch(void* const* d_in, const int* in_sizes, int n_in,
                              void* d_out, int out_size, void* d_ws, size_t ws_size,
                              hipStream_t stream)
{
    const float* item_feat = (const float*)d_in[0];
    const float* gcn_item  = (const float*)d_in[1];
    const float* gcn_user  = (const float*)d_in[2];
    const float* Wi1 = (const float*)d_in[3];
    const float* bi1 = (const float*)d_in[4];
    const float* Wi2 = (const float*)d_in[5];
    const float* bi2 = (const float*)d_in[6];
    const float* Wu1 = (const float*)d_in[7];
    const float* bu1 = (const float*)d_in[8];
    const float* Wu2 = (const float*)d_in[9];
    const float* bu2 = (const float*)d_in[10];
    const int* item_idx = (const int*)d_in[11];
    const int* seg_ids  = (const int*)d_in[12];
    const int* users    = (const int*)d_in[13];
    float* out = (float*)d_out;

    // workspace layout
    char* ws = (char*)d_ws;
    unsigned short* item_emb = (unsigned short*)ws;                         // 51.2 MB
    unsigned short* hist = (unsigned short*)(ws + (size_t)NITEMS * 256);    // 25.6 MB
    size_t off = (size_t)NITEMS * 256 + (size_t)NUSERS * 256;
    int* start = (int*)(ws + off);                                          // 400 KB
    off += ((size_t)(NUSERS + 1) * 4 + 255) & ~(size_t)255;
    unsigned short* W1t  = (unsigned short*)(ws + off); off += 256 * 96 * 2;
    unsigned short* W2t  = (unsigned short*)(ws + off); off += 128 * 256 * 2;
    unsigned short* W1ut = (unsigned short*)(ws + off); off += 256 * 192 * 2;
    unsigned short* W2ut = (unsigned short*)(ws + off);

    // prep: 139264 weight elems + 100001 bound searches
    hipLaunchKernelGGL(prep_kernel, dim3((139264 + NUSERS + 1 + 255) / 256), dim3(256), 0, stream,
                       Wi1, Wi2, Wu1, Wu2, seg_ids, W1t, W2t, W1ut, W2ut, start);

    hipLaunchKernelGGL(item_mfma_kernel, dim3(512), dim3(256), 0, stream,
                       item_feat, gcn_item, W1t, W2t, bi1, bi2, item_emb);

    hipLaunchKernelGGL(seg_mean_kernel, dim3(NUSERS / 4), dim3(256), 0, stream,
                       item_idx, start, item_emb, hist);

    hipLaunchKernelGGL(user_mfma_kernel, dim3(512), dim3(256), 0, stream,
                       gcn_user, hist, W1ut, W2ut, bu1, bu2, users, out);
}